// Round 3
// baseline (11513.552 us; speedup 1.0000x reference)
//
#include <hip/hip_runtime.h>

typedef _Float16 h8 __attribute__((ext_vector_type(8)));
typedef float    f4 __attribute__((ext_vector_type(4)));

// ---------------- workspace layout (bytes) ----------------
// hbuf  : 2*8*16*512 fp16 = 262,144   [parity][ig 8][row 16][k 512] (rows 8..15 unused)
// wflags: 8*32*4          =   1,024   [ig 8][jg*4+w 32]  per-WAVE flags
static const unsigned long long OFF_HBUF  = 0ull;
static const unsigned long long OFF_FLAGS = 262144ull;
static const unsigned long long WS_NEEDED = 263168ull;

__device__ __forceinline__ float sigm(float x)   { return 1.0f / (1.0f + __expf(-x)); }
__device__ __forceinline__ float tanh_a(float x) { return 2.0f / (1.0f + __expf(-2.0f * x)) - 1.0f; }

// ---------------- k_init: zero h double-buffer + flags ----------------
__global__ __launch_bounds__(256) void k_init(_Float16* hbuf, unsigned* wflags)
{
    const int idx = blockIdx.x * 256 + threadIdx.x;
    if (idx < 131072) hbuf[idx] = (_Float16)0.0f;
    if (idx < 256) wflags[idx] = 0u;
}

// ---------------- k_rec: persistent fused LSTM ----------------
// 64 blocks = 8 batch-groups (ig: 8 real rows, MFMA-padded to 16) x 8 unit-groups
// (jg: 64 units). U,V live in VGPRs/AGPRs as MFMA fragments. Gate-init (bias +
// x@U) is h-independent -> computed before the flag wait (shadow work).
// Cross-block h/flag traffic: agent-scope atomics (sc1, through MALL) so
// correctness does not depend on workgroup->XCD mapping. All h stores are
// NATIVE dword atomics (2 fp16 packed via lane-pair shuffle) — 16-bit atomic
// stores lower to CAS loops on AMDGPU (round-2 lesson: ~7 us/step).
__global__ __launch_bounds__(256, 1) void k_rec(
    const float* __restrict__ x,
    const float* __restrict__ Ui, const float* __restrict__ Vi, const float* __restrict__ bi,
    const float* __restrict__ Uf, const float* __restrict__ Vf, const float* __restrict__ bf,
    const float* __restrict__ Uh, const float* __restrict__ Vh, const float* __restrict__ bh,
    const float* __restrict__ Uo, const float* __restrict__ Vo, const float* __restrict__ bo,
    _Float16* hbuf, unsigned* wflags)
{
    const int bx = blockIdx.x;
    const int ig = bx & 7;      // bx&7 -> XCD-affine team (perf heuristic only)
    const int jg = bx >> 3;
    const int tid = threadIdx.x;
    const int w = tid >> 6, l = tid & 63;
    const int lo = l & 15, hi = l >> 4;
    const int unit = jg * 64 + w * 16 + lo;          // hidden unit [0,512)

    const float* Ug[4] = {Ui, Uf, Uh, Uo};
    const float* Vg[4] = {Vi, Vf, Vh, Vo};
    const float* bg[4] = {bi, bf, bh, bo};

    // ---- one-time fragment preload (fp32 -> fp16 cvt) ----
    // B-frag (16x16x32): lane holds B[k = kc*32 + hi*8 + jj][n = lo]
    h8 vfrag[4][16];   // V: K=512 -> 16 k-chunks
    h8 ufrag[4][8];    // U: K=256 ->  8 k-chunks
    float bias[4];
#pragma unroll
    for (int g = 0; g < 4; ++g) {
        bias[g] = bg[g][unit];
#pragma unroll
        for (int kc = 0; kc < 16; ++kc) {
            h8 v;
#pragma unroll
            for (int jj = 0; jj < 8; ++jj)
                v[jj] = (_Float16)Vg[g][(size_t)(kc * 32 + hi * 8 + jj) * 512 + unit];
            vfrag[g][kc] = v;
        }
#pragma unroll
        for (int kc = 0; kc < 8; ++kc) {
            h8 u;
#pragma unroll
            for (int jj = 0; jj < 8; ++jj)
                u[jj] = (_Float16)Ug[g][(size_t)(kc * 32 + hi * 8 + jj) * 512 + unit];
            ufrag[g][kc] = u;
        }
    }

    // A-frag row m = lo; real batch rows 0..7 (rows 8..15 duplicate row lo&7)
    const float* xb = x + (size_t)(ig * 8 + (lo & 7)) * 1024 * 256 + hi * 8;
    unsigned short* hsb = (unsigned short*)hbuf;
    const unsigned* fpoll = wflags + ig * 32 + (l & 31);  // lane-parallel poll of 32 wave-flags
    unsigned* myflag = wflags + ig * 32 + jg * 4 + w;
    const int ueven = jg * 64 + w * 16 + (lo & ~1);       // even unit of my lane pair

    f4 cst = {0.f, 0.f, 0.f, 0.f};   // cell state, C-layout rows hi*4+d

    for (int t = 0; t < 1024; ++t) {
        const int pr = (t + 1) & 1, pw = t & 1;

        // ---- gate-init: bias + x_t @ U (independent of h -> wait-shadow) ----
        h8 xa[8];
        const float* xt = xb + (size_t)t * 256;
#pragma unroll
        for (int kc = 0; kc < 8; ++kc) {
            f4 a0 = *(const f4*)(xt + kc * 32);
            f4 a1 = *(const f4*)(xt + kc * 32 + 4);
            h8 a;
            a[0] = (_Float16)a0[0]; a[1] = (_Float16)a0[1];
            a[2] = (_Float16)a0[2]; a[3] = (_Float16)a0[3];
            a[4] = (_Float16)a1[0]; a[5] = (_Float16)a1[1];
            a[6] = (_Float16)a1[2]; a[7] = (_Float16)a1[3];
            xa[kc] = a;
        }
        f4 acc[4];
#pragma unroll
        for (int g = 0; g < 4; ++g) {
            f4 a; a[0] = bias[g]; a[1] = bias[g]; a[2] = bias[g]; a[3] = bias[g];
            acc[g] = a;
        }
#pragma unroll
        for (int kc = 0; kc < 8; ++kc) {
            acc[0] = __builtin_amdgcn_mfma_f32_16x16x32_f16(xa[kc], ufrag[0][kc], acc[0], 0, 0, 0);
            acc[1] = __builtin_amdgcn_mfma_f32_16x16x32_f16(xa[kc], ufrag[1][kc], acc[1], 0, 0, 0);
            acc[2] = __builtin_amdgcn_mfma_f32_16x16x32_f16(xa[kc], ufrag[2][kc], acc[2], 0, 0, 0);
            acc[3] = __builtin_amdgcn_mfma_f32_16x16x32_f16(xa[kc], ufrag[3][kc], acc[3], 0, 0, 0);
        }

        // ---- wait: all 32 team wave-flags must have published step t-1 ----
        while (__hip_atomic_load(fpoll, __ATOMIC_RELAXED, __HIP_MEMORY_SCOPE_AGENT) < (unsigned)t) {}
        __atomic_signal_fence(__ATOMIC_ACQUIRE);

        // ---- h_{t-1} @ V : coherent 8B atomic loads (bypass stale L1/L2) ----
        const unsigned long long* hp =
            (const unsigned long long*)(hsb + (size_t)((pr * 8 + ig) * 16 + (lo & 7)) * 512 + hi * 8);
#pragma unroll
        for (int kc = 0; kc < 16; ++kc) {
            unsigned long long q0 = __hip_atomic_load(hp + kc * 8,     __ATOMIC_RELAXED, __HIP_MEMORY_SCOPE_AGENT);
            unsigned long long q1 = __hip_atomic_load(hp + kc * 8 + 1, __ATOMIC_RELAXED, __HIP_MEMORY_SCOPE_AGENT);
            union { unsigned long long q; _Float16 h[4]; } u0, u1;
            u0.q = q0; u1.q = q1;
            h8 a;
            a[0] = u0.h[0]; a[1] = u0.h[1]; a[2] = u0.h[2]; a[3] = u0.h[3];
            a[4] = u1.h[0]; a[5] = u1.h[1]; a[6] = u1.h[2]; a[7] = u1.h[3];
            acc[0] = __builtin_amdgcn_mfma_f32_16x16x32_f16(a, vfrag[0][kc], acc[0], 0, 0, 0);
            acc[1] = __builtin_amdgcn_mfma_f32_16x16x32_f16(a, vfrag[1][kc], acc[1], 0, 0, 0);
            acc[2] = __builtin_amdgcn_mfma_f32_16x16x32_f16(a, vfrag[2][kc], acc[2], 0, 0, 0);
            acc[3] = __builtin_amdgcn_mfma_f32_16x16x32_f16(a, vfrag[3][kc], acc[3], 0, 0, 0);
        }

        // ---- elementwise (C-layout: row = hi*4+d, col = unit) ----
        unsigned packed[4];
#pragma unroll
        for (int d = 0; d < 4; ++d) {
            const float iv = sigm(acc[0][d]);
            const float fv = sigm(acc[1][d]);
            const float gv = tanh_a(acc[2][d]);
            const float ov = sigm(acc[3][d]);
            const float c = fv * cst[d] + iv * gv;
            cst[d] = c;
            union { _Float16 h; unsigned short s; } cv;
            cv.h = (_Float16)(ov * tanh_a(c));
            const unsigned mine = (unsigned)cv.s;
            const unsigned part = (unsigned)__shfl_xor((int)mine, 1, 64);
            packed[d] = (mine & 0xffffu) | (part << 16);   // valid on even lanes
        }
        // ---- publish: native dword atomic stores, rows 0..7 only ----
        if (hi < 2 && (lo & 1) == 0) {
            unsigned* hw = (unsigned*)(hsb + (size_t)((pw * 8 + ig) * 16 + hi * 4) * 512 + ueven);
#pragma unroll
            for (int d = 0; d < 4; ++d)
                __hip_atomic_store(hw + (size_t)d * 256, packed[d],
                                   __ATOMIC_RELAXED, __HIP_MEMORY_SCOPE_AGENT);
        }
        // release drains this wave's stores (vmcnt(0)) before flag lands
        if (l == 0)
            __hip_atomic_store(myflag, (unsigned)(t + 1),
                               __ATOMIC_RELEASE, __HIP_MEMORY_SCOPE_AGENT);
    }
}

// ---------------- k_fc: out[b] = h_last[b,:] . fc_w + fc_b ----------------
__global__ __launch_bounds__(64) void k_fc(
    const _Float16* __restrict__ hbuf, const float* __restrict__ fcw,
    const float* __restrict__ fcb, float* __restrict__ out)
{
    const int b = blockIdx.x, l = threadIdx.x;
    // step 1023 lives at parity 1; ig = b>>3, group-local row = b&7
    const _Float16* h = hbuf + (size_t)((8 + (b >> 3)) * 16 + (b & 7)) * 512;
    float s = 0.f;
#pragma unroll
    for (int k = 0; k < 8; ++k) s += (float)h[l + k * 64] * fcw[l + k * 64];
    for (int off = 32; off > 0; off >>= 1) s += __shfl_down(s, off, 64);
    if (l == 0) out[b] = s + fcb[0];
}

__global__ __launch_bounds__(64) void k_sentinel(float* out)
{
    out[threadIdx.x] = -777777.0f;   // signature: ws_size too small
}

extern "C" void kernel_launch(void* const* d_in, const int* in_sizes, int n_in,
                              void* d_out, int out_size, void* d_ws, size_t ws_size,
                              hipStream_t stream)
{
    const float* x   = (const float*)d_in[0];
    const float* Ui  = (const float*)d_in[1];
    const float* Vi  = (const float*)d_in[2];
    const float* bi  = (const float*)d_in[3];
    const float* Uf  = (const float*)d_in[4];
    const float* Vf  = (const float*)d_in[5];
    const float* bf  = (const float*)d_in[6];
    const float* Uh  = (const float*)d_in[7];
    const float* Vh  = (const float*)d_in[8];
    const float* bh  = (const float*)d_in[9];
    const float* Uo  = (const float*)d_in[10];
    const float* Vo  = (const float*)d_in[11];
    const float* bo  = (const float*)d_in[12];
    const float* fcw = (const float*)d_in[13];
    const float* fcb = (const float*)d_in[14];
    float* out = (float*)d_out;

    if (ws_size < WS_NEEDED) {
        k_sentinel<<<1, 64, 0, stream>>>(out);
        return;
    }

    char* ws = (char*)d_ws;
    _Float16* hbuf   = (_Float16*)(ws + OFF_HBUF);
    unsigned* wflags = (unsigned*)(ws + OFF_FLAGS);

    k_init<<<512, 256, 0, stream>>>(hbuf, wflags);
    k_rec <<<64,  256, 0, stream>>>(x, Ui, Vi, bi, Uf, Vf, bf, Uh, Vh, bh,
                                    Uo, Vo, bo, hbuf, wflags);
    k_fc  <<<64,   64, 0, stream>>>(hbuf, fcw, fcb, out);
}

// Round 4
// 8960.947 us; speedup vs baseline: 1.2849x; 1.2849x over previous
//
#include <hip/hip_runtime.h>

typedef _Float16 h8 __attribute__((ext_vector_type(8)));
typedef float    f4 __attribute__((ext_vector_type(4)));

// ---------------- workspace layout (bytes) ----------------
// hbuf  : 2*8*16*512 fp16 = 262,144   [parity][ig 8][row 16][k 512] (rows 8..15 unused)
// wflags: 8*32*4          =   1,024   [ig 8][jg*4+w 32]  per-WAVE flags
static const unsigned long long OFF_HBUF  = 0ull;
static const unsigned long long OFF_FLAGS = 262144ull;
static const unsigned long long WS_NEEDED = 263168ull;

__device__ __forceinline__ float sigm(float x)   { return 1.0f / (1.0f + __expf(-x)); }
__device__ __forceinline__ float tanh_a(float x) { return 2.0f / (1.0f + __expf(-2.0f * x)) - 1.0f; }

// ---------------- k_init: zero h double-buffer + flags ----------------
__global__ __launch_bounds__(256) void k_init(_Float16* hbuf, unsigned* wflags)
{
    const int idx = blockIdx.x * 256 + threadIdx.x;
    if (idx < 131072) hbuf[idx] = (_Float16)0.0f;
    if (idx < 256) wflags[idx] = 0u;
}

// ---------------- k_rec: persistent fused LSTM ----------------
// 64 blocks = 8 batch-groups (ig) x 8 unit-groups (jg: 64 units). U,V live in
// VGPRs as MFMA fragments. Round-4 change: the 32 agent-scope h loads are
// CLUSTERED into q[32] before any use (one pipelined MALL round trip instead
// of 16 serialized ones — round-3 post-mortem), and x_{t+1} is prefetched into
// registers during the h-load latency window.
__global__ __launch_bounds__(256, 1) void k_rec(
    const float* __restrict__ x,
    const float* __restrict__ Ui, const float* __restrict__ Vi, const float* __restrict__ bi,
    const float* __restrict__ Uf, const float* __restrict__ Vf, const float* __restrict__ bf,
    const float* __restrict__ Uh, const float* __restrict__ Vh, const float* __restrict__ bh,
    const float* __restrict__ Uo, const float* __restrict__ Vo, const float* __restrict__ bo,
    _Float16* hbuf, unsigned* wflags)
{
    const int bx = blockIdx.x;
    const int ig = bx & 7;      // bx&7 -> XCD-affine team (perf heuristic only)
    const int jg = bx >> 3;
    const int tid = threadIdx.x;
    const int w = tid >> 6, l = tid & 63;
    const int lo = l & 15, hi = l >> 4;
    const int unit = jg * 64 + w * 16 + lo;          // hidden unit [0,512)

    const float* Ug[4] = {Ui, Uf, Uh, Uo};
    const float* Vg[4] = {Vi, Vf, Vh, Vo};
    const float* bg[4] = {bi, bf, bh, bo};

    // ---- one-time fragment preload (fp32 -> fp16 cvt) ----
    // B-frag (16x16x32): lane holds B[k = kc*32 + hi*8 + jj][n = lo]
    h8 vfrag[4][16];   // V: K=512 -> 16 k-chunks
    h8 ufrag[4][8];    // U: K=256 ->  8 k-chunks
    float bias[4];
#pragma unroll
    for (int g = 0; g < 4; ++g) {
        bias[g] = bg[g][unit];
#pragma unroll
        for (int kc = 0; kc < 16; ++kc) {
            h8 v;
#pragma unroll
            for (int jj = 0; jj < 8; ++jj)
                v[jj] = (_Float16)Vg[g][(size_t)(kc * 32 + hi * 8 + jj) * 512 + unit];
            vfrag[g][kc] = v;
        }
#pragma unroll
        for (int kc = 0; kc < 8; ++kc) {
            h8 u;
#pragma unroll
            for (int jj = 0; jj < 8; ++jj)
                u[jj] = (_Float16)Ug[g][(size_t)(kc * 32 + hi * 8 + jj) * 512 + unit];
            ufrag[g][kc] = u;
        }
    }

    // A-frag row m = lo; real batch rows 0..7 (rows 8..15 duplicate row lo&7)
    const float* xb = x + (size_t)(ig * 8 + (lo & 7)) * 1024 * 256 + hi * 8;
    unsigned short* hsb = (unsigned short*)hbuf;
    const unsigned* fpoll = wflags + ig * 32 + (l & 31);  // lane-parallel poll of 32 wave-flags
    unsigned* myflag = wflags + ig * 32 + jg * 4 + w;
    const int ueven = jg * 64 + w * 16 + (lo & ~1);       // even unit of my lane pair

    f4 cst = {0.f, 0.f, 0.f, 0.f};   // cell state, C-layout rows hi*4+d

    // ---- x prologue: raw fp32 for t=0 (carried in registers) ----
    f4 xr[16];
#pragma unroll
    for (int kc = 0; kc < 8; ++kc) {
        xr[2 * kc]     = *(const f4*)(xb + kc * 32);
        xr[2 * kc + 1] = *(const f4*)(xb + kc * 32 + 4);
    }

    for (int t = 0; t < 1024; ++t) {
        const int pr = (t + 1) & 1, pw = t & 1;

        // ---- cvt carried x_t -> fp16 A-frags ----
        h8 xa[8];
#pragma unroll
        for (int kc = 0; kc < 8; ++kc) {
            const f4 a0 = xr[2 * kc], a1 = xr[2 * kc + 1];
            h8 a;
            a[0] = (_Float16)a0[0]; a[1] = (_Float16)a0[1];
            a[2] = (_Float16)a0[2]; a[3] = (_Float16)a0[3];
            a[4] = (_Float16)a1[0]; a[5] = (_Float16)a1[1];
            a[6] = (_Float16)a1[2]; a[7] = (_Float16)a1[3];
            xa[kc] = a;
        }

        // ---- gate-init: bias + x_t @ U (h-independent wait-shadow work) ----
        f4 acc[4];
#pragma unroll
        for (int g = 0; g < 4; ++g) {
            f4 a; a[0] = bias[g]; a[1] = bias[g]; a[2] = bias[g]; a[3] = bias[g];
            acc[g] = a;
        }
#pragma unroll
        for (int kc = 0; kc < 8; ++kc) {
            acc[0] = __builtin_amdgcn_mfma_f32_16x16x32_f16(xa[kc], ufrag[0][kc], acc[0], 0, 0, 0);
            acc[1] = __builtin_amdgcn_mfma_f32_16x16x32_f16(xa[kc], ufrag[1][kc], acc[1], 0, 0, 0);
            acc[2] = __builtin_amdgcn_mfma_f32_16x16x32_f16(xa[kc], ufrag[2][kc], acc[2], 0, 0, 0);
            acc[3] = __builtin_amdgcn_mfma_f32_16x16x32_f16(xa[kc], ufrag[3][kc], acc[3], 0, 0, 0);
        }

        // ---- wait: all 32 team wave-flags must have published step t-1 ----
        while (__hip_atomic_load(fpoll, __ATOMIC_RELAXED, __HIP_MEMORY_SCOPE_AGENT) < (unsigned)t) {}
        __atomic_signal_fence(__ATOMIC_ACQUIRE);

        // ---- CLUSTERED h_{t-1} loads: 32 back-to-back atomic 8B loads ----
        const unsigned long long* hp =
            (const unsigned long long*)(hsb + (size_t)((pr * 8 + ig) * 16 + (lo & 7)) * 512 + hi * 8);
        unsigned long long q[32];
#pragma unroll
        for (int kc = 0; kc < 16; ++kc) {
            q[2 * kc]     = __hip_atomic_load(hp + kc * 8,     __ATOMIC_RELAXED, __HIP_MEMORY_SCOPE_AGENT);
            q[2 * kc + 1] = __hip_atomic_load(hp + kc * 8 + 1, __ATOMIC_RELAXED, __HIP_MEMORY_SCOPE_AGENT);
        }

        // ---- prefetch x_{t+1} during the h-load latency window ----
        {
            const float* xtn = xb + (size_t)((t < 1023) ? t + 1 : t) * 256;
#pragma unroll
            for (int kc = 0; kc < 8; ++kc) {
                xr[2 * kc]     = *(const f4*)(xtn + kc * 32);
                xr[2 * kc + 1] = *(const f4*)(xtn + kc * 32 + 4);
            }
        }

        // ---- h_{t-1} @ V ----
#pragma unroll
        for (int kc = 0; kc < 16; ++kc) {
            union { unsigned long long q; _Float16 h[4]; } u0, u1;
            u0.q = q[2 * kc]; u1.q = q[2 * kc + 1];
            h8 a;
            a[0] = u0.h[0]; a[1] = u0.h[1]; a[2] = u0.h[2]; a[3] = u0.h[3];
            a[4] = u1.h[0]; a[5] = u1.h[1]; a[6] = u1.h[2]; a[7] = u1.h[3];
            acc[0] = __builtin_amdgcn_mfma_f32_16x16x32_f16(a, vfrag[0][kc], acc[0], 0, 0, 0);
            acc[1] = __builtin_amdgcn_mfma_f32_16x16x32_f16(a, vfrag[1][kc], acc[1], 0, 0, 0);
            acc[2] = __builtin_amdgcn_mfma_f32_16x16x32_f16(a, vfrag[2][kc], acc[2], 0, 0, 0);
            acc[3] = __builtin_amdgcn_mfma_f32_16x16x32_f16(a, vfrag[3][kc], acc[3], 0, 0, 0);
        }

        // ---- elementwise (C-layout: row = hi*4+d, col = unit) ----
        unsigned packed[4];
#pragma unroll
        for (int d = 0; d < 4; ++d) {
            const float iv = sigm(acc[0][d]);
            const float fv = sigm(acc[1][d]);
            const float gv = tanh_a(acc[2][d]);
            const float ov = sigm(acc[3][d]);
            const float c = fv * cst[d] + iv * gv;
            cst[d] = c;
            union { _Float16 h; unsigned short s; } cv;
            cv.h = (_Float16)(ov * tanh_a(c));
            const unsigned mine = (unsigned)cv.s;
            const unsigned part = (unsigned)__shfl_xor((int)mine, 1, 64);
            packed[d] = (mine & 0xffffu) | (part << 16);   // valid on even lanes
        }
        // ---- publish: native dword atomic stores, rows 0..7 only ----
        if (hi < 2 && (lo & 1) == 0) {
            unsigned* hw = (unsigned*)(hsb + (size_t)((pw * 8 + ig) * 16 + hi * 4) * 512 + ueven);
#pragma unroll
            for (int d = 0; d < 4; ++d)
                __hip_atomic_store(hw + (size_t)d * 256, packed[d],
                                   __ATOMIC_RELAXED, __HIP_MEMORY_SCOPE_AGENT);
        }
        // release drains this wave's stores (vmcnt(0)) before flag lands
        if (l == 0)
            __hip_atomic_store(myflag, (unsigned)(t + 1),
                               __ATOMIC_RELEASE, __HIP_MEMORY_SCOPE_AGENT);
    }
}

// ---------------- k_fc: out[b] = h_last[b,:] . fc_w + fc_b ----------------
__global__ __launch_bounds__(64) void k_fc(
    const _Float16* __restrict__ hbuf, const float* __restrict__ fcw,
    const float* __restrict__ fcb, float* __restrict__ out)
{
    const int b = blockIdx.x, l = threadIdx.x;
    // step 1023 lives at parity 1; ig = b>>3, group-local row = b&7
    const _Float16* h = hbuf + (size_t)((8 + (b >> 3)) * 16 + (b & 7)) * 512;
    float s = 0.f;
#pragma unroll
    for (int k = 0; k < 8; ++k) s += (float)h[l + k * 64] * fcw[l + k * 64];
    for (int off = 32; off > 0; off >>= 1) s += __shfl_down(s, off, 64);
    if (l == 0) out[b] = s + fcb[0];
}

__global__ __launch_bounds__(64) void k_sentinel(float* out)
{
    out[threadIdx.x] = -777777.0f;   // signature: ws_size too small
}

extern "C" void kernel_launch(void* const* d_in, const int* in_sizes, int n_in,
                              void* d_out, int out_size, void* d_ws, size_t ws_size,
                              hipStream_t stream)
{
    const float* x   = (const float*)d_in[0];
    const float* Ui  = (const float*)d_in[1];
    const float* Vi  = (const float*)d_in[2];
    const float* bi  = (const float*)d_in[3];
    const float* Uf  = (const float*)d_in[4];
    const float* Vf  = (const float*)d_in[5];
    const float* bf  = (const float*)d_in[6];
    const float* Uh  = (const float*)d_in[7];
    const float* Vh  = (const float*)d_in[8];
    const float* bh  = (const float*)d_in[9];
    const float* Uo  = (const float*)d_in[10];
    const float* Vo  = (const float*)d_in[11];
    const float* bo  = (const float*)d_in[12];
    const float* fcw = (const float*)d_in[13];
    const float* fcb = (const float*)d_in[14];
    float* out = (float*)d_out;

    if (ws_size < WS_NEEDED) {
        k_sentinel<<<1, 64, 0, stream>>>(out);
        return;
    }

    char* ws = (char*)d_ws;
    _Float16* hbuf   = (_Float16*)(ws + OFF_HBUF);
    unsigned* wflags = (unsigned*)(ws + OFF_FLAGS);

    k_init<<<512, 256, 0, stream>>>(hbuf, wflags);
    k_rec <<<64,  256, 0, stream>>>(x, Ui, Vi, bi, Uf, Vf, bf, Uh, Vh, bh,
                                    Uo, Vo, bo, hbuf, wflags);
    k_fc  <<<64,   64, 0, stream>>>(hbuf, fcw, fcb, out);
}